// Round 5
// baseline (31.136 us; speedup 1.0000x reference)
//
#include <hip/hip_runtime.h>
#include <math.h>

// GRU(64 -> hidden=1), one timestep. rows = B*N = 524288,
// row = [h, x0..x63] contiguous f32 (65 floats = 260 B).
//
// R4 structure: NO LDS, NO barriers, NO shuffles.
//  - row-per-lane: each lane streams its 65 floats via scalar global loads
//    (wave covers a contiguous 16.6 KB region; every line fetched once).
//  - weights are wave-uniform -> compiler scalarizes to s_load; FMAs take
//    the weight as an SGPR operand. Zero LDS traffic, zero barrier drains;
//    loads stay in flight across compute at the compiler's discretion.

#define THREADS 256

__device__ __forceinline__ float sigmoidf_(float v) {
    return 1.0f / (1.0f + __expf(-v));
}

__global__ __launch_bounds__(THREADS)
void gru_cell_kernel(const float* __restrict__ inputs,
                     const float* __restrict__ W_ih,   // [3][64]
                     const float* __restrict__ W_hh,   // [3]
                     const float* __restrict__ b_ih,   // [3]
                     const float* __restrict__ b_hh,   // [3]
                     const float* __restrict__ w_out,  // [1]
                     const float* __restrict__ b_out,  // [1]
                     float* __restrict__ out,
                     int nrows)
{
    const size_t row_idx = (size_t)blockIdx.x * THREADS + threadIdx.x;
    if (row_idx >= (size_t)nrows) return;

    const float* __restrict__ row = inputs + row_idx * 65;

    const float h = row[0];

    // 3 dot products of length 64; weight operands are wave-uniform (SGPR).
    float a0 = 0.0f, a1 = 0.0f, a2 = 0.0f;
    #pragma unroll
    for (int j = 0; j < 64; ++j) {
        const float xv = row[1 + j];
        a0 = fmaf(xv, W_ih[j],       a0);
        a1 = fmaf(xv, W_ih[64 + j],  a1);
        a2 = fmaf(xv, W_ih[128 + j], a2);
    }

    const float gh0 = fmaf(h, W_hh[0], b_hh[0]);
    const float gh1 = fmaf(h, W_hh[1], b_hh[1]);
    const float gh2 = fmaf(h, W_hh[2], b_hh[2]);

    const float rg = sigmoidf_(a0 + b_ih[0] + gh0);
    const float zg = sigmoidf_(a1 + b_ih[1] + gh1);
    const float ng = tanhf(a2 + b_ih[2] + rg * gh2);
    const float h_new = (1.0f - zg) * ng + zg * h;

    out[row_idx] = fmaf(h_new, w_out[0], b_out[0]);
}

extern "C" void kernel_launch(void* const* d_in, const int* in_sizes, int n_in,
                              void* d_out, int out_size, void* d_ws, size_t ws_size,
                              hipStream_t stream) {
    const float* inputs = (const float*)d_in[0];
    const float* W_ih   = (const float*)d_in[1];
    const float* W_hh   = (const float*)d_in[2];
    const float* b_ih   = (const float*)d_in[3];
    const float* b_hh   = (const float*)d_in[4];
    const float* w_out  = (const float*)d_in[5];
    const float* b_out  = (const float*)d_in[6];
    float* out = (float*)d_out;

    const int nrows  = in_sizes[0] / 65;            // 524288
    const int blocks = (nrows + THREADS - 1) / THREADS;   // 2048

    gru_cell_kernel<<<dim3(blocks), dim3(THREADS), 0, stream>>>(
        inputs, W_ih, W_hh, b_ih, b_hh, w_out, b_out, out, nrows);
}

// Round 6
// 26.369 us; speedup vs baseline: 1.1808x; 1.1808x over previous
//
#include <hip/hip_runtime.h>
#include <math.h>

// GRU(64 -> hidden=1), one timestep. rows = B*N = 524288,
// row = [h, x0..x63] contiguous f32 (65 floats = 260 B).
//
// R5: persistent double-buffered structure.
//  - 2048 blocks x 128 threads; each block processes 8 contiguous regions
//    of 32 rows (8320 B) via LDS double-buffer.
//  - Per iteration: barrier (drains stage of cur) -> issue async stage of
//    NEXT region into other buffer -> compute cur. Prefetch has the whole
//    compute phase to land; drained by the next barrier (which needs it).
//  - Compute: 4 lanes per row, quarter-row dot + shfl_xor reduce (R3).

#define THREADS 128
#define RPB 32                    // rows per region
#define ROW_F 65                  // floats per row
#define REGION_F (RPB * ROW_F)    // 2080 floats = 8320 B
#define FULL_ITERS 4              // 4 x (128 threads x 16 B) = 8192 B
#define NBLOCKS 2048

__device__ __forceinline__ float sigmoidf_(float v) {
    return 1.0f / (1.0f + __expf(-v));
}

__device__ __forceinline__ void async_copy16(const void* g, void* l) {
    __builtin_amdgcn_global_load_lds(
        (const __attribute__((address_space(1))) void*)g,
        (__attribute__((address_space(3))) void*)l,
        16, 0, 0);
}

__device__ __forceinline__ void stage_region(const float* __restrict__ inputs,
                                             size_t region, float* buf, int tid)
{
    const char* gsrc = (const char*)(inputs + region * REGION_F);
    const int wave_off = (tid >> 6) << 10;   // wave_id * 1024 B
    #pragma unroll
    for (int it = 0; it < FULL_ITERS; ++it) {
        async_copy16(gsrc + it * 2048 + tid * 16,
                     (char*)buf + it * 2048 + wave_off);
    }
    // 128 B tail: lanes 0..7 of wave 0 (uniform LDS base; HW adds lane*16)
    if (tid < 8) {
        async_copy16(gsrc + 8192 + tid * 16, (char*)buf + 8192);
    }
}

__global__ __launch_bounds__(THREADS)
void gru_cell_kernel(const float* __restrict__ inputs,
                     const float* __restrict__ W_ih,   // [3][64]
                     const float* __restrict__ W_hh,   // [3]
                     const float* __restrict__ b_ih,   // [3]
                     const float* __restrict__ b_hh,   // [3]
                     const float* __restrict__ w_out,  // [1]
                     const float* __restrict__ b_out,  // [1]
                     float* __restrict__ out,
                     int iters)
{
    __shared__ float ldsRow[2][REGION_F];  // 2 x 8320 B
    __shared__ float ldsW[192];            // 768 B: W_ih 3x64

    const int tid = threadIdx.x;

    // weights once per block
    if (tid < 48) {
        reinterpret_cast<float4*>(ldsW)[tid] =
            reinterpret_cast<const float4*>(W_ih)[tid];
    }

    const size_t region0 = (size_t)blockIdx.x * iters;
    stage_region(inputs, region0, ldsRow[0], tid);

    const int r = tid >> 2;          // row 0..31
    const int q = tid & 3;           // quarter 0..3
    const float* w0 = ldsW +   0 + q * 16;
    const float* w1 = ldsW +  64 + q * 16;
    const float* w2 = ldsW + 128 + q * 16;

    // scalar params (uniform; L1 broadcast)
    const float Whh0 = W_hh[0], Whh1 = W_hh[1], Whh2 = W_hh[2];
    const float bh0 = b_hh[0], bh1 = b_hh[1], bh2 = b_hh[2];
    const float bi0 = b_ih[0], bi1 = b_ih[1], bi2 = b_ih[2];
    const float wo = w_out[0], bo = b_out[0];

    for (int i = 0; i < iters; ++i) {
        __syncthreads();   // drains stage(i); also clears WAR on buf[(i+1)&1]

        if (i + 1 < iters) {
            stage_region(inputs, region0 + i + 1, ldsRow[(i + 1) & 1], tid);
        }

        const float* buf = ldsRow[i & 1];
        const float* x = buf + r * ROW_F + 1 + q * 16;

        float a0 = 0.0f, a1 = 0.0f, a2 = 0.0f;
        #pragma unroll
        for (int j = 0; j < 16; ++j) {
            const float xv = x[j];
            a0 = fmaf(xv, w0[j], a0);
            a1 = fmaf(xv, w1[j], a1);
            a2 = fmaf(xv, w2[j], a2);
        }

        a0 += __shfl_xor(a0, 1); a0 += __shfl_xor(a0, 2);
        a1 += __shfl_xor(a1, 1); a1 += __shfl_xor(a1, 2);
        a2 += __shfl_xor(a2, 1); a2 += __shfl_xor(a2, 2);

        const float h = buf[r * ROW_F];
        const float gh0 = fmaf(h, Whh0, bh0);
        const float gh1 = fmaf(h, Whh1, bh1);
        const float gh2 = fmaf(h, Whh2, bh2);

        const float rg = sigmoidf_(a0 + bi0 + gh0);
        const float zg = sigmoidf_(a1 + bi1 + gh1);
        const float ng = tanhf(a2 + bi2 + rg * gh2);
        const float h_new = (1.0f - zg) * ng + zg * h;

        if (q == 0) {
            out[(region0 + i) * RPB + r] = fmaf(h_new, wo, bo);
        }
    }
}

extern "C" void kernel_launch(void* const* d_in, const int* in_sizes, int n_in,
                              void* d_out, int out_size, void* d_ws, size_t ws_size,
                              hipStream_t stream) {
    const float* inputs = (const float*)d_in[0];
    const float* W_ih   = (const float*)d_in[1];
    const float* W_hh   = (const float*)d_in[2];
    const float* b_ih   = (const float*)d_in[3];
    const float* b_hh   = (const float*)d_in[4];
    const float* w_out  = (const float*)d_in[5];
    const float* b_out  = (const float*)d_in[6];
    float* out = (float*)d_out;

    const int nrows    = in_sizes[0] / ROW_F;   // 524288
    const int nregions = nrows / RPB;           // 16384
    const int iters    = nregions / NBLOCKS;    // 8 (exact)

    gru_cell_kernel<<<dim3(NBLOCKS), dim3(THREADS), 0, stream>>>(
        inputs, W_ih, W_hh, b_ih, b_hh, w_out, b_out, out, iters);
}